// Round 7
// baseline (27.091 us; speedup 1.0000x reference)
//
#include <hip/hip_runtime.h>

// Problem constants (setup_inputs: [16, 3, 512, 512] fp32)
#define HW       262144     // 512*512 (power of two: 2^18)
#define HWV      65536      // HW/4: float4 vecs per channel-image
#define CH       HW         // channel stride (elements)
#define BSTRIDE  (3*HW)     // batch stride (elements)
#define NELEM_INV (1.0f / 12582912.0f)   // 1 / (16*3*512*512)

#define GRID1    2048
#define BLOCK1   256
#define VPB      512        // vec-indices per block (2 per thread); 512 | HWV -> no image straddle

typedef float f4 __attribute__((ext_vector_type(4)));

__device__ __forceinline__ f4 vload(const float* p) {
    return *reinterpret_cast<const f4*>(p);   // global_load_dwordx4 (cached)
}

__device__ __forceinline__ float cbrt_fast(float t) {
    // t > 0 on the taken branch; cbrt(t) = exp2(log2(t)/3) via v_log_f32/v_exp_f32
    return __builtin_amdgcn_exp2f(0.33333333333333f * __builtin_amdgcn_logf(t));
}

__device__ __forceinline__ float f_lab(float t) {
    const float T0 = 0.008856f;
    return (t > T0) ? cbrt_fast(t) : (7.787f * t + 16.0f / 116.0f);
}

__device__ __forceinline__ float3 rgb2lab_n(float r, float g, float b) {
    const float XN_INV = 1.0f / 0.950456f;
    const float ZN_INV = 1.0f / 1.088754f;
    const float T0 = 0.008856f;
    float x = (0.412453f * r + 0.35758f  * g + 0.180423f * b) * XN_INV;
    float y =  0.212671f * r + 0.71516f  * g + 0.072169f * b;
    float z = (0.019334f * r + 0.119193f * g + 0.950227f * b) * ZN_INV;
    float fx = f_lab(x);
    float fy = f_lab(y);
    float fz = f_lab(z);
    float L  = (y > T0) ? (116.0f * fy - 16.0f) : (903.3f * y);
    float a  = 500.0f * (fx - fy);
    float bb = 200.0f * (fy - fz);
    return make_float3(L * 0.01f,
                       (a  + 128.0f) * (1.0f / 255.0f),
                       (bb + 128.0f) * (1.0f / 255.0f));
}

__device__ __forceinline__ float pix_loss(float pr, float pg, float pb,
                                          float tr, float tg, float tb) {
    float3 p = rgb2lab_n(pr, pg, pb);
    float3 t = rgb2lab_n(tr, tg, tb);
    float dL = p.x - t.x;
    float da = p.y - t.y;
    float db = p.z - t.z;
    return dL * dL + da * da + db * db;
}

__device__ __forceinline__ float quad_loss(const f4& pr, const f4& pg, const f4& pb,
                                           const f4& tr, const f4& tg, const f4& tb) {
    float a;
    a  = pix_loss(pr.x, pg.x, pb.x, tr.x, tg.x, tb.x);
    a += pix_loss(pr.y, pg.y, pb.y, tr.y, tg.y, tb.y);
    a += pix_loss(pr.z, pg.z, pb.z, tr.z, tg.z, tb.z);
    a += pix_loss(pr.w, pg.w, pb.w, tr.w, tg.w, tb.w);
    return a;
}

__global__ __launch_bounds__(BLOCK1, 4) void cc_partial(
        const float* __restrict__ pred,
        const float* __restrict__ tgt,
        float* __restrict__ part) {
    // Block-contiguous assignment: block b owns vec range [b*VPB, b*VPB+VPB).
    // 512 | HWV, so the whole block lies in one image: batch idx is uniform.
    const int vbase = blockIdx.x * VPB;                // block's first vec index
    const int batch = vbase >> 16;                     // vbase / HWV
    const size_t ebase = (size_t)batch * BSTRIDE + ((vbase & (HWV - 1)) << 2);

    const int e0 = threadIdx.x << 2;                   // elem offset of iter 0
    const int e1 = e0 + (BLOCK1 << 2);                 // iter 1: +1024 elems (adjacent 4KB run)

    const float* pp = pred + ebase;
    const float* tp = tgt  + ebase;

    // 12 upfront loads; 6 contiguous 8KB streams per block.
    const f4 pr0 = vload(pp + e0);
    const f4 pg0 = vload(pp + e0 + CH);
    const f4 pb0 = vload(pp + e0 + 2 * CH);
    const f4 tr0 = vload(tp + e0);
    const f4 tg0 = vload(tp + e0 + CH);
    const f4 tb0 = vload(tp + e0 + 2 * CH);
    const f4 pr1 = vload(pp + e1);
    const f4 pg1 = vload(pp + e1 + CH);
    const f4 pb1 = vload(pp + e1 + 2 * CH);
    const f4 tr1 = vload(tp + e1);
    const f4 tg1 = vload(tp + e1 + CH);
    const f4 tb1 = vload(tp + e1 + 2 * CH);

    float acc = quad_loss(pr0, pg0, pb0, tr0, tg0, tb0)
              + quad_loss(pr1, pg1, pb1, tr1, tg1, tb1);

    // wave (64-lane) shuffle reduce
    #pragma unroll
    for (int off = 32; off > 0; off >>= 1)
        acc += __shfl_down(acc, off);

    __shared__ float smem[BLOCK1 / 64];
    const int lane = threadIdx.x & 63;
    const int wid  = threadIdx.x >> 6;
    if (lane == 0) smem[wid] = acc;
    __syncthreads();
    if (threadIdx.x == 0) {
        float s = 0.0f;
        #pragma unroll
        for (int w = 0; w < BLOCK1 / 64; ++w) s += smem[w];
        part[blockIdx.x] = s;
    }
}

__global__ __launch_bounds__(256) void cc_final(
        const float* __restrict__ part,
        float* __restrict__ out,
        int nparts) {
    float acc = 0.0f;
    for (int i = threadIdx.x; i < nparts; i += 256)
        acc += part[i];

    #pragma unroll
    for (int off = 32; off > 0; off >>= 1)
        acc += __shfl_down(acc, off);

    __shared__ float smem[4];
    const int lane = threadIdx.x & 63;
    const int wid  = threadIdx.x >> 6;
    if (lane == 0) smem[wid] = acc;
    __syncthreads();
    if (threadIdx.x == 0) {
        float s = smem[0] + smem[1] + smem[2] + smem[3];
        out[0] = s * NELEM_INV;   // WEIGHT = 1.0
    }
}

extern "C" void kernel_launch(void* const* d_in, const int* in_sizes, int n_in,
                              void* d_out, int out_size, void* d_ws, size_t ws_size,
                              hipStream_t stream) {
    const float* pred = (const float*)d_in[0];
    const float* tgt  = (const float*)d_in[1];
    float* out  = (float*)d_out;
    float* part = (float*)d_ws;   // GRID1 floats = 8 KiB scratch

    cc_partial<<<GRID1, BLOCK1, 0, stream>>>(pred, tgt, part);
    cc_final<<<1, 256, 0, stream>>>(part, out, GRID1);
}

// Round 8
// 23.403 us; speedup vs baseline: 1.1576x; 1.1576x over previous
//
#include <hip/hip_runtime.h>

// Problem constants (setup_inputs: [16, 3, 512, 512] fp32)
#define HW       262144     // 512*512
#define HWV      65536      // HW/4: float4 vecs per channel-image
#define CH       HW         // channel stride (elements)
#define BSTRIDE  (3*HW)     // batch stride (elements)
#define NELEM_INV (1.0f / 12582912.0f)   // 1 / (16*3*512*512)

#define GRID1    4096
#define BLOCK1   256        // 4096*256*1 vec = NVEC exactly; 256 | HWV -> no image straddle

typedef float f4 __attribute__((ext_vector_type(4)));

__device__ __forceinline__ f4 vload(const float* p) {
    return *reinterpret_cast<const f4*>(p);   // global_load_dwordx4 (cached)
}

__device__ __forceinline__ float cbrt_fast(float t) {
    // t > 0 on the taken branch; cbrt(t) = exp2(log2(t)/3) via v_log_f32/v_exp_f32
    return __builtin_amdgcn_exp2f(0.33333333333333f * __builtin_amdgcn_logf(t));
}

__device__ __forceinline__ float f_lab(float t) {
    const float T0 = 0.008856f;
    return (t > T0) ? cbrt_fast(t) : fmaf(7.787f, t, 16.0f / 116.0f);
}

// Returns {fx, fy, fz, y}. XYZ matrix has /XN, /ZN folded into coefficients.
__device__ __forceinline__ f4 lab_f(float r, float g, float b) {
    float x = fmaf(0.433953f, r, fmaf(0.376219f, g, 0.189828f * b));
    float y = fmaf(0.212671f, r, fmaf(0.715160f, g, 0.072169f * b));
    float z = fmaf(0.017758f, r, fmaf(0.109477f, g, 0.872766f * b));
    f4 o;
    o.x = f_lab(x);
    o.y = f_lab(y);
    o.z = f_lab(z);
    o.w = y;
    return o;
}

__device__ __forceinline__ float pix_loss(float pr, float pg, float pb,
                                          float tr, float tg, float tb) {
    const float T0 = 0.008856f;
    f4 P = lab_f(pr, pg, pb);
    f4 T = lab_f(tr, tg, tb);
    // L/100 folded: 1.16*fy - 0.16  vs  9.033*y
    float Lp = (P.w > T0) ? fmaf(1.16f, P.y, -0.16f) : 9.033f * P.w;
    float Lt = (T.w > T0) ? fmaf(1.16f, T.y, -0.16f) : 9.033f * T.w;
    float dL = Lp - Lt;
    // (a+128)/255 diffs collapse: da = (500/255)(u-v), db = (200/255)(v-w)
    float u = P.x - T.x;
    float v = P.y - T.y;
    float w = P.z - T.z;
    float da = (u - v) * (500.0f / 255.0f);
    float db = (v - w) * (200.0f / 255.0f);
    return fmaf(dL, dL, fmaf(da, da, db * db));
}

__device__ __forceinline__ float quad_loss(const f4& pr, const f4& pg, const f4& pb,
                                           const f4& tr, const f4& tg, const f4& tb) {
    float a;
    a  = pix_loss(pr.x, pg.x, pb.x, tr.x, tg.x, tb.x);
    a += pix_loss(pr.y, pg.y, pb.y, tr.y, tg.y, tb.y);
    a += pix_loss(pr.z, pg.z, pb.z, tr.z, tg.z, tb.z);
    a += pix_loss(pr.w, pg.w, pb.w, tr.w, tg.w, tb.w);
    return a;
}

__global__ __launch_bounds__(BLOCK1, 4) void cc_partial(
        const float* __restrict__ pred,
        const float* __restrict__ tgt,
        float* __restrict__ part) {
    // Fine granularity: block b owns vec range [b*256, b*256+256) — one vec/thread.
    const int vbase = blockIdx.x << 8;
    const int batch = vbase >> 16;                     // vbase / HWV (uniform per block)
    const size_t ebase = (size_t)batch * BSTRIDE + (size_t)((vbase & (HWV - 1)) << 2);

    const float* pp = pred + ebase + (threadIdx.x << 2);
    const float* tp = tgt  + ebase + (threadIdx.x << 2);

    const f4 pr = vload(pp);
    const f4 pg = vload(pp + CH);
    const f4 pb = vload(pp + 2 * CH);
    const f4 tr = vload(tp);
    const f4 tg = vload(tp + CH);
    const f4 tb = vload(tp + 2 * CH);

    float acc = quad_loss(pr, pg, pb, tr, tg, tb);

    // wave (64-lane) shuffle reduce
    #pragma unroll
    for (int off = 32; off > 0; off >>= 1)
        acc += __shfl_down(acc, off);

    __shared__ float smem[BLOCK1 / 64];
    const int lane = threadIdx.x & 63;
    const int wid  = threadIdx.x >> 6;
    if (lane == 0) smem[wid] = acc;
    __syncthreads();
    if (threadIdx.x == 0) {
        float s = 0.0f;
        #pragma unroll
        for (int w = 0; w < BLOCK1 / 64; ++w) s += smem[w];
        part[blockIdx.x] = s;
    }
}

__global__ __launch_bounds__(256) void cc_final(
        const float* __restrict__ part,
        float* __restrict__ out) {
    // 4096 partials: thread t sums floats [16t, 16t+16) via 4 f4 loads.
    const float* p = part + (threadIdx.x << 4);
    f4 a0 = vload(p);
    f4 a1 = vload(p + 4);
    f4 a2 = vload(p + 8);
    f4 a3 = vload(p + 12);
    float acc = (a0.x + a0.y + a0.z + a0.w) + (a1.x + a1.y + a1.z + a1.w)
              + (a2.x + a2.y + a2.z + a2.w) + (a3.x + a3.y + a3.z + a3.w);

    #pragma unroll
    for (int off = 32; off > 0; off >>= 1)
        acc += __shfl_down(acc, off);

    __shared__ float smem[4];
    const int lane = threadIdx.x & 63;
    const int wid  = threadIdx.x >> 6;
    if (lane == 0) smem[wid] = acc;
    __syncthreads();
    if (threadIdx.x == 0) {
        float s = smem[0] + smem[1] + smem[2] + smem[3];
        out[0] = s * NELEM_INV;   // WEIGHT = 1.0
    }
}

extern "C" void kernel_launch(void* const* d_in, const int* in_sizes, int n_in,
                              void* d_out, int out_size, void* d_ws, size_t ws_size,
                              hipStream_t stream) {
    const float* pred = (const float*)d_in[0];
    const float* tgt  = (const float*)d_in[1];
    float* out  = (float*)d_out;
    float* part = (float*)d_ws;   // 4096 floats = 16 KiB scratch

    cc_partial<<<GRID1, BLOCK1, 0, stream>>>(pred, tgt, part);
    cc_final<<<1, 256, 0, stream>>>(part, out);
}

// Round 9
// 23.344 us; speedup vs baseline: 1.1605x; 1.0025x over previous
//
#include <hip/hip_runtime.h>

// Problem constants (setup_inputs: [16, 3, 512, 512] fp32)
#define HW       262144     // 512*512
#define HWV      65536      // HW/4: float4 vecs per channel-image
#define CH       HW         // channel stride (elements)
#define BSTRIDE  (3*HW)     // batch stride (elements)
#define NELEM_INV (1.0f / 12582912.0f)   // 1 / (16*3*512*512)

#define GRID1    4096
#define BLOCK1   256        // 4096*256*1 vec = NVEC exactly; 256 | HWV -> no image straddle

typedef float f4 __attribute__((ext_vector_type(4)));

__device__ __forceinline__ f4 vload(const float* p) {
    return *reinterpret_cast<const f4*>(p);   // global_load_dwordx4 (cached)
}

__device__ __forceinline__ float cbrt_fast(float t) {
    // t > 0 on the taken branch; cbrt(t) = exp2(log2(t)/3) via v_log_f32/v_exp_f32
    return __builtin_amdgcn_exp2f(0.33333333333333f * __builtin_amdgcn_logf(t));
}

__device__ __forceinline__ float f_lab(float t) {
    const float T0 = 0.008856f;
    return (t > T0) ? cbrt_fast(t) : fmaf(7.787f, t, 16.0f / 116.0f);
}

// Returns {fx, fy, fz, y}. XYZ matrix has /XN, /ZN folded into coefficients.
__device__ __forceinline__ f4 lab_f(float r, float g, float b) {
    float x = fmaf(0.433953f, r, fmaf(0.376219f, g, 0.189828f * b));
    float y = fmaf(0.212671f, r, fmaf(0.715160f, g, 0.072169f * b));
    float z = fmaf(0.017758f, r, fmaf(0.109477f, g, 0.872766f * b));
    f4 o;
    o.x = f_lab(x);
    o.y = f_lab(y);
    o.z = f_lab(z);
    o.w = y;
    return o;
}

__device__ __forceinline__ float pix_loss(float pr, float pg, float pb,
                                          float tr, float tg, float tb) {
    const float T0 = 0.008856f;
    f4 P = lab_f(pr, pg, pb);
    f4 T = lab_f(tr, tg, tb);
    // L/100 folded: 1.16*fy - 0.16  vs  9.033*y
    float Lp = (P.w > T0) ? fmaf(1.16f, P.y, -0.16f) : 9.033f * P.w;
    float Lt = (T.w > T0) ? fmaf(1.16f, T.y, -0.16f) : 9.033f * T.w;
    float dL = Lp - Lt;
    // (a+128)/255 diffs collapse: da = (500/255)(u-v), db = (200/255)(v-w)
    float u = P.x - T.x;
    float v = P.y - T.y;
    float w = P.z - T.z;
    float da = (u - v) * (500.0f / 255.0f);
    float db = (v - w) * (200.0f / 255.0f);
    return fmaf(dL, dL, fmaf(da, da, db * db));
}

__device__ __forceinline__ float quad_loss(const f4& pr, const f4& pg, const f4& pb,
                                           const f4& tr, const f4& tg, const f4& tb) {
    float a;
    a  = pix_loss(pr.x, pg.x, pb.x, tr.x, tg.x, tb.x);
    a += pix_loss(pr.y, pg.y, pb.y, tr.y, tg.y, tb.y);
    a += pix_loss(pr.z, pg.z, pb.z, tr.z, tg.z, tb.z);
    a += pix_loss(pr.w, pg.w, pb.w, tr.w, tg.w, tb.w);
    return a;
}

// (256, 8): 8 waves/SIMD target -> VGPR cap 64. Kernel needs ~48 live VGPRs
// (6 f4 payloads + addresses + working), so this should fit without spill and
// double resident waves vs the previous (256,4) cap that pinned occupancy at 58%.
__global__ __launch_bounds__(BLOCK1, 8) void cc_partial(
        const float* __restrict__ pred,
        const float* __restrict__ tgt,
        float* __restrict__ part) {
    // Fine granularity: block b owns vec range [b*256, b*256+256) — one vec/thread.
    const int vbase = blockIdx.x << 8;
    const int batch = vbase >> 16;                     // vbase / HWV (uniform per block)
    const size_t ebase = (size_t)batch * BSTRIDE + (size_t)((vbase & (HWV - 1)) << 2);

    const float* pp = pred + ebase + (threadIdx.x << 2);
    const float* tp = tgt  + ebase + (threadIdx.x << 2);

    const f4 pr = vload(pp);
    const f4 pg = vload(pp + CH);
    const f4 pb = vload(pp + 2 * CH);
    const f4 tr = vload(tp);
    const f4 tg = vload(tp + CH);
    const f4 tb = vload(tp + 2 * CH);

    float acc = quad_loss(pr, pg, pb, tr, tg, tb);

    // wave (64-lane) shuffle reduce
    #pragma unroll
    for (int off = 32; off > 0; off >>= 1)
        acc += __shfl_down(acc, off);

    __shared__ float smem[BLOCK1 / 64];
    const int lane = threadIdx.x & 63;
    const int wid  = threadIdx.x >> 6;
    if (lane == 0) smem[wid] = acc;
    __syncthreads();
    if (threadIdx.x == 0) {
        float s = 0.0f;
        #pragma unroll
        for (int w = 0; w < BLOCK1 / 64; ++w) s += smem[w];
        part[blockIdx.x] = s;
    }
}

__global__ __launch_bounds__(256) void cc_final(
        const float* __restrict__ part,
        float* __restrict__ out) {
    // 4096 partials: thread t sums floats [16t, 16t+16) via 4 f4 loads.
    const float* p = part + (threadIdx.x << 4);
    f4 a0 = vload(p);
    f4 a1 = vload(p + 4);
    f4 a2 = vload(p + 8);
    f4 a3 = vload(p + 12);
    float acc = (a0.x + a0.y + a0.z + a0.w) + (a1.x + a1.y + a1.z + a1.w)
              + (a2.x + a2.y + a2.z + a2.w) + (a3.x + a3.y + a3.z + a3.w);

    #pragma unroll
    for (int off = 32; off > 0; off >>= 1)
        acc += __shfl_down(acc, off);

    __shared__ float smem[4];
    const int lane = threadIdx.x & 63;
    const int wid  = threadIdx.x >> 6;
    if (lane == 0) smem[wid] = acc;
    __syncthreads();
    if (threadIdx.x == 0) {
        float s = smem[0] + smem[1] + smem[2] + smem[3];
        out[0] = s * NELEM_INV;   // WEIGHT = 1.0
    }
}

extern "C" void kernel_launch(void* const* d_in, const int* in_sizes, int n_in,
                              void* d_out, int out_size, void* d_ws, size_t ws_size,
                              hipStream_t stream) {
    const float* pred = (const float*)d_in[0];
    const float* tgt  = (const float*)d_in[1];
    float* out  = (float*)d_out;
    float* part = (float*)d_ws;   // 4096 floats = 16 KiB scratch

    cc_partial<<<GRID1, BLOCK1, 0, stream>>>(pred, tgt, part);
    cc_final<<<1, 256, 0, stream>>>(part, out);
}